// Round 10
// baseline (223.989 us; speedup 1.0000x reference)
//
#include <hip/hip_runtime.h>

typedef unsigned short u16;
typedef unsigned int u32;
typedef short short8 __attribute__((ext_vector_type(8)));
typedef float f32x4 __attribute__((ext_vector_type(4)));
typedef float f32x16 __attribute__((ext_vector_type(16)));

#define NB 4
#define NS 2048
#define NSTATE 1024
#define NH 16
#define ND 64
#define NM (NB*NS)   // 8192 rows

#if __has_builtin(__builtin_amdgcn_exp2f)
#define EXP2(x) __builtin_amdgcn_exp2f(x)
#else
#define EXP2(x) __expf((x) * 0.6931471805599453f)
#endif

__device__ __forceinline__ u16 f2bf(float f){
  union { float fv; unsigned uv; } x; x.fv = f;
  unsigned r = x.uv + 0x7fffu + ((x.uv >> 16) & 1u);
  return (u16)(r >> 16);
}

__device__ __forceinline__ u32 cvtpk(float lo, float hi){
  u32 r;
  asm("v_cvt_pk_bf16_f32 %0, %1, %2" : "=v"(r) : "v"(lo), "v"(hi));
  return r;
}

__device__ __forceinline__ f32x4 mfma16x16(short8 a, short8 b, f32x4 c){
  return __builtin_amdgcn_mfma_f32_16x16x32_bf16(a, b, c, 0, 0, 0);
}

__device__ __forceinline__ f32x16 mfma32(short8 a, short8 b, f32x16 c){
  return __builtin_amdgcn_mfma_f32_32x32x16_bf16(a, b, c, 0, 0, 0);
}

__device__ __forceinline__ void gld_lds16(const u16* g, u16* l){
  __builtin_amdgcn_global_load_lds((const __attribute__((address_space(1))) void*)g,
                                   (__attribute__((address_space(3))) void*)l, 16, 0, 0);
}

#define FENCE() __builtin_amdgcn_sched_barrier(0)

// ---------------- fp32 -> bf16 conversion for 3 activations + 4 weights ----
__global__ __launch_bounds__(256)
void cvt_all(const float* __restrict__ q, const float* __restrict__ k, const float* __restrict__ v,
             const float* __restrict__ wq, const float* __restrict__ wk,
             const float* __restrict__ wv, const float* __restrict__ wo,
             u16* oq, u16* ok, u16* ov, u16* owq, u16* owk, u16* owv, u16* owo){
  const int XN4 = (NB*NS*NSTATE)/4;   // 2097152
  const int WN4 = (NSTATE*NSTATE)/4;  // 262144
  int gid = blockIdx.x * 256 + threadIdx.x;
  const float* src; u16* dst; int idx;
  if (gid < XN4)          { src = q; dst = oq; idx = gid; }
  else if (gid < 2*XN4)   { src = k; dst = ok; idx = gid - XN4; }
  else if (gid < 3*XN4)   { src = v; dst = ov; idx = gid - 2*XN4; }
  else {
    int g = gid - 3*XN4;
    int wsel = g >> 18;       // / WN4
    idx = g & (WN4 - 1);
    src = (wsel==0)?wq:(wsel==1)?wk:(wsel==2)?wv:wo;
    dst = (wsel==0)?owq:(wsel==1)?owk:(wsel==2)?owv:owo;
  }
  float4 val = ((const float4*)src)[idx];
  ushort4 r;
  r.x = f2bf(val.x); r.y = f2bf(val.y); r.z = f2bf(val.z); r.w = f2bf(val.w);
  ((ushort4*)dst)[idx] = r;
}

// ---------------- merged QKV projection GEMM, 256^2 tile, deep pipeline ----
// BM=BN=256, BK=32, 512 threads (8 waves 2Mx4N, per-wave 128x64 out).
// LDS: 4 buffers x (A 256x32 + B 256x32) bf16 = 128 KB. Stage tile t+3 while
// computing t; tiles t+1,t+2 in flight; counted s_waitcnt vmcnt(8) (4 loads
// per tile per thread, FIFO retire) -> no vmcnt(0) drain in the main loop.
// Raw s_barrier (NOT __syncthreads -- that inserts a vmcnt(0) drain).
// Output cols [0,1024)=Q(RoPE), [1024,2048)=K(RoPE), [2048,3072)=V (written
// transposed to Vt[B,H,D,S] straight from fragments). Grid 384, XCD-chunked.
__global__ __launch_bounds__(512)
void gemm_qkv(const u16* __restrict__ xq, const u16* __restrict__ xk,
              const u16* __restrict__ xv, const u16* __restrict__ Wcat,
              u16* __restrict__ Qh, u16* __restrict__ Kk, u16* __restrict__ Vt){
  __shared__ __align__(16) u16 Ab[4][256*32];
  __shared__ __align__(16) u16 Bb[4][256*32];
  const int gblk = blockIdx.x;
  const int wid = (gblk & 7) * 48 + (gblk >> 3);   // bijective: 384 = 8*48
  const int bx = wid % 12, by = wid / 12;
  const int sel = bx >> 2;                          // 0=Q 1=K 2=V
  const u16* A = (sel==0) ? xq : (sel==1) ? xk : xv;
  const int tid = threadIdx.x;
  const int lane = tid & 63, w = tid >> 6;
  const int wr = w >> 2, wc = w & 3;                // 2M x 4N waves
  const int l15 = lane & 15, lhi = lane >> 4;
  const int brow = by*256, bcol = bx*256;
  const int K = NSTATE;

  f32x4 acc[8][4] = {};

  // stage K-tile t (BK=32) into buffer b: per-thread 2 A-chunks + 2 B-chunks.
  // XOR swizzle (both-sides): source col-chunk = cc ^ (row&3), LDS linear.
  auto stage = [&](int t, int b){
    const int kt = t*32;
    #pragma unroll
    for (int i2 = 0; i2 < 2; ++i2){
      int ch = i2*512 + tid;              // 1024 chunks of 16B (256 rows x 4)
      int row = ch >> 2, cc = ch & 3;
      int scc = cc ^ (row & 3);
      gld_lds16(A + (size_t)(brow+row)*K + kt + scc*8, &Ab[b][ch*8]);
    }
    #pragma unroll
    for (int i2 = 0; i2 < 2; ++i2){
      int ch = i2*512 + tid;
      int row = ch >> 2, cc = ch & 3;
      int scc = cc ^ (row & 3);
      gld_lds16(Wcat + (size_t)(bcol+row)*K + kt + scc*8, &Bb[b][ch*8]);
    }
  };

  auto compute = [&](int b){
    const u16* Ax = &Ab[b][0];
    const u16* Bx = &Bb[b][0];
    #pragma unroll
    for (int ih = 0; ih < 2; ++ih){
      short8 av[4];
      #pragma unroll
      for (int i = 0; i < 4; ++i){
        int row = wr*128 + ih*64 + i*16 + l15;
        av[i] = *(const short8*)&Ax[row*32 + ((lhi ^ (row&3))*8)];
      }
      #pragma unroll
      for (int jh = 0; jh < 2; ++jh){
        short8 bv[2];
        #pragma unroll
        for (int j = 0; j < 2; ++j){
          int row = wc*64 + jh*32 + j*16 + l15;
          bv[j] = *(const short8*)&Bx[row*32 + ((lhi ^ (row&3))*8)];
        }
        __builtin_amdgcn_s_setprio(1);
        #pragma unroll
        for (int i = 0; i < 4; ++i)
          #pragma unroll
          for (int j = 0; j < 2; ++j)
            acc[ih*4+i][jh*2+j] = mfma16x16(av[i], bv[j], acc[ih*4+i][jh*2+j]);
        __builtin_amdgcn_s_setprio(0);
      }
    }
  };

  // prologue: tiles 0,1,2 in flight (12 loads/thread)
  stage(0, 0); stage(1, 1); stage(2, 2);

  #pragma unroll 1
  for (int t = 0; t < 29; ++t){
    asm volatile("s_waitcnt vmcnt(8)" ::: "memory");   // tile t landed
    FENCE(); __builtin_amdgcn_s_barrier(); FENCE();
    stage(t+3, (t+3)&3);    // overwrites buf read at t-1 (barrier-protected)
    compute(t&3);
  }
  asm volatile("s_waitcnt vmcnt(8)" ::: "memory");
  FENCE(); __builtin_amdgcn_s_barrier(); FENCE();
  compute(29&3);
  asm volatile("s_waitcnt vmcnt(4)" ::: "memory");
  FENCE(); __builtin_amdgcn_s_barrier(); FENCE();
  compute(30&3);
  asm volatile("s_waitcnt vmcnt(0)" ::: "memory");
  FENCE(); __builtin_amdgcn_s_barrier(); FENCE();
  compute(31&3);

  // ---- epilogue ----
  const int col0 = bcol + wc*64;                  // wave's 64-col slab (one head)
  if (sel == 2){
    // V -> Vt[B,H,D,S]: 4 acc regs = 4 consecutive s at fixed d.
    const int head = (col0 & 1023) >> 6;
    #pragma unroll
    for (int i = 0; i < 8; ++i){
      int m0 = brow + wr*128 + i*16 + lhi*4;
      int b = m0 >> 11, s0 = m0 & (NS-1);
      u16* obase = Vt + ((size_t)((b*NH + head)*ND))*NS + s0;
      #pragma unroll
      for (int j = 0; j < 4; ++j){
        int d = j*16 + l15;
        uint2 pk;
        pk.x = cvtpk(acc[i][j][0], acc[i][j][1]);
        pk.y = cvtpk(acc[i][j][2], acc[i][j][3]);
        *(uint2*)(obase + (size_t)d*NS) = pk;
      }
    }
  } else {
    // Q/K: scale (incl sqrt(log2e)) + RoPE, write [B,H,S,D]
    u16* out = sel ? Kk : Qh;
    const float qk_scale = 0.4246609f;            // (1/8)^0.5 * sqrt(log2 e)
    const int head = (col0 & 1023) >> 6;
    const float invf = EXP2(-0.83048202f * (float)l15);   // 10000^(-l15/16)
    #pragma unroll
    for (int i = 0; i < 8; ++i){
      #pragma unroll
      for (int reg = 0; reg < 4; ++reg){
        int m = brow + wr*128 + i*16 + lhi*4 + reg;
        int b = m >> 11, s = m & (NS-1);
        float sn, cs;
        __sincosf((float)s * invf, &sn, &cs);
        float x0 = acc[i][0][reg]*qk_scale;
        float x1 = acc[i][1][reg]*qk_scale;
        u16* orow = out + ((size_t)(b*NH + head)*NS + s)*ND;
        orow[ 0 + l15] = f2bf(x0*cs - x1*sn);
        orow[16 + l15] = f2bf(x1*cs + x0*sn);
        orow[32 + l15] = f2bf(acc[i][2][reg]*qk_scale);
        orow[48 + l15] = f2bf(acc[i][3][reg]*qk_scale);
      }
    }
  }
}

// ---------------- Wo GEMM: fp32 out, flat grid 512, XCD-swizzled -----------
__global__ __launch_bounds__(256)
void gemm_wo(const u16* __restrict__ A, const u16* __restrict__ Bt, float* __restrict__ out){
  __shared__ __align__(16) u16 As[128*64];
  __shared__ __align__(16) u16 Bs[128*64];
  const int gblk = blockIdx.x;
  const int wid = (gblk & 7) * 64 + (gblk >> 3);
  const int bx = wid & 7, by = wid >> 3;
  const int tid = threadIdx.x;
  const int lane = tid & 63, w = tid >> 6;
  const int wr = w >> 1, wc = w & 1;
  const int l15 = lane & 15, lhi = lane >> 4;
  const int brow = by * 128;
  const int bcol = bx * 128;
  const int K = NSTATE;
  f32x4 acc[4][4] = {};

  for (int kt = 0; kt < K; kt += 64){
    #pragma unroll
    for (int it = 0; it < 4; ++it){
      int flat = it*4096 + tid*16;
      int row = flat >> 7, colb = flat & 127;
      gld_lds16(A + (size_t)(brow+row)*K + kt + (colb>>1), As + (flat>>1));
    }
    #pragma unroll
    for (int it = 0; it < 4; ++it){
      int flat = it*4096 + tid*16;
      int row = flat >> 7, colb = flat & 127;
      gld_lds16(Bt + (size_t)(bcol+row)*K + kt + (colb>>1), Bs + (flat>>1));
    }
    __syncthreads();
    #pragma unroll
    for (int ks = 0; ks < 2; ++ks){
      short8 av[4], bv[4];
      #pragma unroll
      for (int i = 0; i < 4; ++i)
        av[i] = *(const short8*)&As[(wr*64 + i*16 + l15)*64 + ks*32 + lhi*8];
      #pragma unroll
      for (int j = 0; j < 4; ++j)
        bv[j] = *(const short8*)&Bs[(wc*64 + j*16 + l15)*64 + ks*32 + lhi*8];
      #pragma unroll
      for (int i = 0; i < 4; ++i)
        #pragma unroll
        for (int j = 0; j < 4; ++j)
          acc[i][j] = mfma16x16(av[i], bv[j], acc[i][j]);
    }
    __syncthreads();
  }
  #pragma unroll
  for (int i = 0; i < 4; ++i)
    #pragma unroll
    for (int reg = 0; reg < 4; ++reg){
      int m = brow + wr*64 + i*16 + lhi*4 + reg;
      float* orow = out + (size_t)m*NSTATE + bcol + wc*64;
      #pragma unroll
      for (int j = 0; j < 4; ++j)
        orow[j*16 + l15] = acc[i][j][reg];
    }
}

// ---------------- causal flash attention (32x32 swapped-QK, T12) ----------
// (unchanged from R9 -- session-best structure)
__global__ __launch_bounds__(256)
void flash_attn(const u16* __restrict__ Q, const u16* __restrict__ Kh,
                const u16* __restrict__ Vt, u16* __restrict__ O){
  __shared__ __align__(16) u16 Kbuf[2][64*64];
  __shared__ __align__(16) u16 Vbuf[2][64*64];
  const int gblk = blockIdx.x;
  const int xcd = gblk & 7, gr = gblk >> 3;     // 128 blocks per XCD
  const int bh  = xcd*8 + (gr & 7);             // 8 consecutive bh per XCD
  const int g   = 15 - (gr >> 3);               // long groups first
  const int tid = threadIdx.x;
  const int w = tid >> 6, lane = tid & 63;
  const int l31 = lane & 31, hi = lane >> 5;
  const u16* Qb = Q  + (size_t)bh*NS*ND;
  const u16* Kb = Kh + (size_t)bh*NS*ND;
  const u16* Vb = Vt + (size_t)bh*ND*NS;
  const int b = bh >> 4, h = bh & 15;
  const int qw = g*128 + w*32;
  const int kend_w   = qw + 32;
  const int kend_blk = g*128 + 128;

  short8 qf[4];
  #pragma unroll
  for (int dd = 0; dd < 4; ++dd)
    qf[dd] = *(const short8*)&Qb[(size_t)(qw + l31)*ND + dd*16 + hi*8];

  f32x16 oacc[2] = {};
  float mrun = 8.0f, lrun = 0.f;

  int cur = 0;
  #pragma unroll
  for (int i = 0; i < 2; ++i){
    int ch = i*256 + tid;
    int row = ch >> 3, cc = ch & 7;
    int scc = cc ^ (row & 7);
    gld_lds16(Kb + (size_t)row*ND + scc*8, &Kbuf[cur][ch*8]);
    gld_lds16(Vb + (size_t)row*NS + scc*8, &Vbuf[cur][ch*8]);
  }
  __syncthreads();

  #pragma unroll 1
  for (int kv0 = 0; kv0 < kend_blk; kv0 += 64){
    if (kv0 + 64 < kend_blk){
      #pragma unroll
      for (int i = 0; i < 2; ++i){
        int ch = i*256 + tid;
        int row = ch >> 3, cc = ch & 7;
        int scc = cc ^ (row & 7);
        gld_lds16(Kb + (size_t)(kv0 + 64 + row)*ND + scc*8, &Kbuf[cur^1][ch*8]);
        gld_lds16(Vb + (size_t)row*NS + kv0 + 64 + scc*8, &Vbuf[cur^1][ch*8]);
      }
    }
    if (kv0 < kend_w){
      const char* kb = (const char*)&Kbuf[cur][0];
      const char* vb = (const char*)&Vbuf[cur][0];
      short8 kf[8];
      #pragma unroll
      for (int kh2 = 0; kh2 < 2; ++kh2)
        #pragma unroll
        for (int dd = 0; dd < 4; ++dd){
          int srow = kh2*32 + l31;
          int off = (srow*128 + dd*32 + hi*16) ^ ((srow & 7) << 4);
          kf[kh2*4+dd] = *(const short8*)(kb + off);
        }
      f32x16 st0 = {}, st1 = {};
      __builtin_amdgcn_s_setprio(1);
      #pragma unroll
      for (int dd = 0; dd < 4; ++dd) st0 = mfma32(kf[dd],   qf[dd], st0);
      #pragma unroll
      for (int dd = 0; dd < 4; ++dd) st1 = mfma32(kf[4+dd], qf[dd], st1);
      __builtin_amdgcn_s_setprio(0);
      if (kv0 + 63 > qw){
        int q = qw + l31;
        #pragma unroll
        for (int r2 = 0; r2 < 16; ++r2){
          int k0 = kv0 + (r2 & 3) + 8*(r2 >> 2) + 4*hi;
          if (k0      > q) st0[r2] = -3.0e30f;
          if (k0 + 32 > q) st1[r2] = -3.0e30f;
        }
      }
      float m0 = fmaxf(fmaxf(st0[0], st0[1]), fmaxf(st0[2], st0[3]));
      float m1 = fmaxf(fmaxf(st0[4], st0[5]), fmaxf(st0[6], st0[7]));
      float m2 = fmaxf(fmaxf(st0[8], st0[9]), fmaxf(st0[10], st0[11]));
      float m3 = fmaxf(fmaxf(st0[12], st0[13]), fmaxf(st0[14], st0[15]));
      float m4 = fmaxf(fmaxf(st1[0], st1[1]), fmaxf(st1[2], st1[3]));
      float m5 = fmaxf(fmaxf(st1[4], st1[5]), fmaxf(st1[6], st1[7]));
      float m6 = fmaxf(fmaxf(st1[8], st1[9]), fmaxf(st1[10], st1[11]));
      float m7 = fmaxf(fmaxf(st1[12], st1[13]), fmaxf(st1[14], st1[15]));
      float pm = fmaxf(fmaxf(fmaxf(m0, m1), fmaxf(m2, m3)),
                       fmaxf(fmaxf(m4, m5), fmaxf(m6, m7)));
      pm = fmaxf(pm, __shfl_xor(pm, 32));
      #pragma unroll
      for (int r2 = 0; r2 < 16; ++r2){
        st0[r2] = EXP2(st0[r2] - mrun);
        st1[r2] = EXP2(st1[r2] - mrun);
      }
      float s0 = 0.f, s1 = 0.f, s2 = 0.f, s3 = 0.f;
      #pragma unroll
      for (int r2 = 0; r2 < 16; r2 += 4){
        s0 += st0[r2+0] + st1[r2+0];
        s1 += st0[r2+1] + st1[r2+1];
        s2 += st0[r2+2] + st1[r2+2];
        s3 += st0[r2+3] + st1[r2+3];
      }
      float rs = (s0 + s1) + (s2 + s3);
      rs += __shfl_xor(rs, 32);
      if (__any(pm > mrun)){
        float mn = fmaxf(mrun, pm);
        float a  = EXP2(mrun - mn);
        mrun = mn;
        lrun = (lrun + rs) * a;
        #pragma unroll
        for (int r2 = 0; r2 < 16; ++r2){
          st0[r2] *= a; st1[r2] *= a;
          oacc[0][r2] *= a; oacc[1][r2] *= a;
        }
      } else {
        lrun += rs;
      }
      short8 paf[4];
      #pragma unroll
      for (int sl = 0; sl < 4; ++sl){
        const f32x16& S = (sl < 2) ? st0 : st1;
        const int base = (sl & 1) * 8;
        u32 a0 = cvtpk(S[base+0], S[base+1]);
        u32 b0 = cvtpk(S[base+4], S[base+5]);
        asm("v_permlane32_swap_b32 %0, %1" : "+v"(a0), "+v"(b0));
        u32 a1 = cvtpk(S[base+2], S[base+3]);
        u32 b1 = cvtpk(S[base+6], S[base+7]);
        asm("v_permlane32_swap_b32 %0, %1" : "+v"(a1), "+v"(b1));
        union { u32 u[4]; short8 v; } pk_;
        pk_.u[0] = a0; pk_.u[1] = a1; pk_.u[2] = b0; pk_.u[3] = b1;
        paf[sl] = pk_.v;
      }
      #pragma unroll
      for (int dh = 0; dh < 2; ++dh){
        short8 vv[4];
        #pragma unroll
        for (int sl = 0; sl < 4; ++sl){
          int drow = dh*32 + l31;
          int off = (drow*128 + sl*32 + hi*16) ^ ((drow & 7) << 4);
          vv[sl] = *(const short8*)(vb + off);
        }
        __builtin_amdgcn_s_setprio(1);
        #pragma unroll
        for (int sl = 0; sl < 4; ++sl)
          oacc[dh] = mfma32(vv[sl], paf[sl], oacc[dh]);
        __builtin_amdgcn_s_setprio(0);
      }
    }
    __syncthreads();
    cur ^= 1;
  }

  float inv = 1.0f / lrun;
  u16* orow = O + ((size_t)(b*NS + qw + l31))*NSTATE + h*ND;
  #pragma unroll
  for (int dh = 0; dh < 2; ++dh)
    #pragma unroll
    for (int rq = 0; rq < 4; ++rq){
      uint2 pk;
      pk.x = cvtpk(oacc[dh][rq*4+0]*inv, oacc[dh][rq*4+1]*inv);
      pk.y = cvtpk(oacc[dh][rq*4+2]*inv, oacc[dh][rq*4+3]*inv);
      *(uint2*)(orow + dh*32 + rq*8 + hi*4) = pk;
    }
}

// ---------------------------------------------------------------------------
extern "C" void kernel_launch(void* const* d_in, const int* in_sizes, int n_in,
                              void* d_out, int out_size, void* d_ws, size_t ws_size,
                              hipStream_t stream){
  const float* q_src = (const float*)d_in[0];
  const float* k_src = (const float*)d_in[1];
  const float* v_src = (const float*)d_in[2];
  // d_in[3] = position_mask (causal, statically known) — unused
  const float* Wq = (const float*)d_in[4];
  const float* Wk = (const float*)d_in[5];
  const float* Wv = (const float*)d_in[6];
  const float* Wo = (const float*)d_in[7];

  char* ws = (char*)d_ws;
  const size_t MB = 1u << 20;
  if (ws_size < 104*MB) return;   // need 104 MB of scratch

  u16* xq   = (u16*)(ws +  0*MB);   // 16 MB  (bf16 q_src)
  u16* xk   = (u16*)(ws + 16*MB);   // 16 MB  (bf16 k_src)   -> reused as attn out
  u16* xv   = (u16*)(ws + 32*MB);   // 16 MB  (bf16 v_src)
  u16* wq16 = (u16*)(ws + 48*MB);   //  2 MB  } contiguous => Wcat [3072][1024]
  u16* wk16 = (u16*)(ws + 50*MB);   //  2 MB  }
  u16* wv16 = (u16*)(ws + 52*MB);   //  2 MB  }
  u16* wo16 = (u16*)(ws + 54*MB);   //  2 MB
  u16* Qh   = (u16*)(ws + 56*MB);   // 16 MB  [B,H,S,D]
  u16* Kk   = (u16*)(ws + 72*MB);   // 16 MB  [B,H,S,D]
  u16* Vt   = (u16*)(ws + 88*MB);   // 16 MB  [B,H,D,S]  (direct from gemm_qkv)
  u16* Oat  = xk;                   // [B,S,H*D]  (xk dead after QKV gemm)

  cvt_all<<<dim3(28672), dim3(256), 0, stream>>>(q_src, k_src, v_src, Wq, Wk, Wv, Wo,
                                                 xq, xk, xv, wq16, wk16, wv16, wo16);
  gemm_qkv<<<dim3(384), dim3(512), 0, stream>>>(xq, xk, xv, wq16, Qh, Kk, Vt);
  flash_attn<<<dim3(1024), dim3(256), 0, stream>>>(Qh, Kk, Vt, Oat);
  gemm_wo<<<dim3(512), dim3(256), 0, stream>>>(Oat, wo16, (float*)d_out);
}

// Round 11
// 196.345 us; speedup vs baseline: 1.1408x; 1.1408x over previous
//
#include <hip/hip_runtime.h>

typedef unsigned short u16;
typedef unsigned int u32;
typedef short short8 __attribute__((ext_vector_type(8)));
typedef float f32x4 __attribute__((ext_vector_type(4)));
typedef float f32x16 __attribute__((ext_vector_type(16)));

#define NB 4
#define NS 2048
#define NSTATE 1024
#define NH 16
#define ND 64
#define NM (NB*NS)   // 8192 rows

#if __has_builtin(__builtin_amdgcn_exp2f)
#define EXP2(x) __builtin_amdgcn_exp2f(x)
#else
#define EXP2(x) __expf((x) * 0.6931471805599453f)
#endif

__device__ __forceinline__ u16 f2bf(float f){
  union { float fv; unsigned uv; } x; x.fv = f;
  unsigned r = x.uv + 0x7fffu + ((x.uv >> 16) & 1u);
  return (u16)(r >> 16);
}

__device__ __forceinline__ u32 cvtpk(float lo, float hi){
  u32 r;
  asm("v_cvt_pk_bf16_f32 %0, %1, %2" : "=v"(r) : "v"(lo), "v"(hi));
  return r;
}

__device__ __forceinline__ f32x4 mfma16x16(short8 a, short8 b, f32x4 c){
  return __builtin_amdgcn_mfma_f32_16x16x32_bf16(a, b, c, 0, 0, 0);
}

__device__ __forceinline__ f32x16 mfma32(short8 a, short8 b, f32x16 c){
  return __builtin_amdgcn_mfma_f32_32x32x16_bf16(a, b, c, 0, 0, 0);
}

__device__ __forceinline__ void gld_lds16(const u16* g, u16* l){
  __builtin_amdgcn_global_load_lds((const __attribute__((address_space(1))) void*)g,
                                   (__attribute__((address_space(3))) void*)l, 16, 0, 0);
}

// ---------------- fp32 -> bf16 conversion for 3 activations + 4 weights ----
__global__ __launch_bounds__(256)
void cvt_all(const float* __restrict__ q, const float* __restrict__ k, const float* __restrict__ v,
             const float* __restrict__ wq, const float* __restrict__ wk,
             const float* __restrict__ wv, const float* __restrict__ wo,
             u16* oq, u16* ok, u16* ov, u16* owq, u16* owk, u16* owv, u16* owo){
  const int XN4 = (NB*NS*NSTATE)/4;   // 2097152
  const int WN4 = (NSTATE*NSTATE)/4;  // 262144
  int gid = blockIdx.x * 256 + threadIdx.x;
  const float* src; u16* dst; int idx;
  if (gid < XN4)          { src = q; dst = oq; idx = gid; }
  else if (gid < 2*XN4)   { src = k; dst = ok; idx = gid - XN4; }
  else if (gid < 3*XN4)   { src = v; dst = ov; idx = gid - 2*XN4; }
  else {
    int g = gid - 3*XN4;
    int wsel = g >> 18;       // / WN4
    idx = g & (WN4 - 1);
    src = (wsel==0)?wq:(wsel==1)?wk:(wsel==2)?wv:wo;
    dst = (wsel==0)?owq:(wsel==1)?owk:(wsel==2)?owv:owo;
  }
  float4 val = ((const float4*)src)[idx];
  ushort4 r;
  r.x = f2bf(val.x); r.y = f2bf(val.y); r.z = f2bf(val.z); r.w = f2bf(val.w);
  ((ushort4*)dst)[idx] = r;
}

// ---------------- merged QKV projection GEMM (R9 structure + XOR swizzle) --
// 128^2 tile, BK=64, 256 thr (2x2 waves, 64x64/wave), single-buffer LDS 32KB
// -> 4 blocks/CU. Both-sides XOR swizzle on As/Bs: global source chunk
// cb^(row&7) staged to linear LDS; fragment reads use the same XOR. This
// kills the [128][64]-row-major ds_read_b128 bank conflict (R9: 18.9M cyc
// = ~33% of dispatch). Output cols [0,1024)=Q(RoPE), [1024,2048)=K(RoPE),
// [2048,3072)=V written transposed to Vt[B,H,D,S]. Grid 1536, XCD-swizzled.
__global__ __launch_bounds__(256)
void gemm_qkv(const u16* __restrict__ xq, const u16* __restrict__ xk,
              const u16* __restrict__ xv, const u16* __restrict__ Wcat,
              u16* __restrict__ Qh, u16* __restrict__ Kk, u16* __restrict__ Vt){
  __shared__ __align__(16) u16 As[128*64];
  __shared__ __align__(16) u16 Bs[128*64];
  const int gblk = blockIdx.x;
  const int wid = (gblk & 7) * 192 + (gblk >> 3);
  const int bx = wid % 24, by = wid / 24;
  const int sel = bx >> 3;                        // 0=Q 1=K 2=V
  const u16* A = (sel==0) ? xq : (sel==1) ? xk : xv;
  const int tid = threadIdx.x;
  const int lane = tid & 63, w = tid >> 6;
  const int wr = w >> 1, wc = w & 1;
  const int l15 = lane & 15, lhi = lane >> 4;
  const int brow = by * 128;
  const int bcol = bx * 128;                      // global col in [0,3072)
  const int K = NSTATE;
  f32x4 acc[4][4] = {};

  for (int kt = 0; kt < K; kt += 64){
    #pragma unroll
    for (int it = 0; it < 4; ++it){               // stage A tile 128x64
      int flat = it*4096 + tid*16;                // byte index in tile
      int row = flat >> 7;
      int cb  = (flat >> 4) & 7;                  // 16B chunk in row
      int scb = cb ^ (row & 7);                   // inverse-swizzled source
      gld_lds16(A + (size_t)(brow+row)*K + kt + scb*8, As + (flat>>1));
    }
    #pragma unroll
    for (int it = 0; it < 4; ++it){               // stage B tile 128x64
      int flat = it*4096 + tid*16;
      int row = flat >> 7;
      int cb  = (flat >> 4) & 7;
      int scb = cb ^ (row & 7);
      gld_lds16(Wcat + (size_t)(bcol+row)*K + kt + scb*8, Bs + (flat>>1));
    }
    __syncthreads();
    #pragma unroll
    for (int ks = 0; ks < 2; ++ks){
      short8 av[4], bv[4];
      #pragma unroll
      for (int i = 0; i < 4; ++i){
        int row = wr*64 + i*16 + l15;
        av[i] = *(const short8*)&As[row*64 + (((ks*4 + lhi) ^ (row & 7))*8)];
      }
      #pragma unroll
      for (int j = 0; j < 4; ++j){
        int row = wc*64 + j*16 + l15;
        bv[j] = *(const short8*)&Bs[row*64 + (((ks*4 + lhi) ^ (row & 7))*8)];
      }
      __builtin_amdgcn_s_setprio(1);
      #pragma unroll
      for (int i = 0; i < 4; ++i)
        #pragma unroll
        for (int j = 0; j < 4; ++j)
          acc[i][j] = mfma16x16(av[i], bv[j], acc[i][j]);
      __builtin_amdgcn_s_setprio(0);
    }
    __syncthreads();
  }

  const int col0 = bcol + wc*64;                  // wave's 64-col slab (one head)
  if (sel == 2){
    // V -> Vt[B,H,D,S] directly: d = j*16+l15, s0 = (m of reg 0) & 2047.
    const int head = (col0 & 1023) >> 6;
    #pragma unroll
    for (int i = 0; i < 4; ++i){
      int m0 = brow + wr*64 + i*16 + lhi*4;       // reg 0 row (4 consecutive s)
      int b = m0 >> 11, s0 = m0 & (NS-1);
      u16* obase = Vt + ((size_t)((b*NH + head)*ND))*NS + s0;
      #pragma unroll
      for (int j = 0; j < 4; ++j){
        int d = j*16 + l15;
        uint2 pk;
        pk.x = cvtpk(acc[i][j][0], acc[i][j][1]);
        pk.y = cvtpk(acc[i][j][2], acc[i][j][3]);
        *(uint2*)(obase + (size_t)d*NS) = pk;
      }
    }
  } else {
    // Q/K: scale (incl sqrt(log2e)) + RoPE, write [B,H,S,D]
    u16* out = sel ? Kk : Qh;
    const float qk_scale = 0.4246609f;            // (1/8)^0.5 * sqrt(log2 e)
    const int head = (col0 & 1023) >> 6;
    const float invf = EXP2(-0.83048202f * (float)l15);   // 10000^(-l15/16)
    #pragma unroll
    for (int i = 0; i < 4; ++i){
      #pragma unroll
      for (int reg = 0; reg < 4; ++reg){
        int m = brow + wr*64 + i*16 + lhi*4 + reg;
        int b = m >> 11, s = m & (NS-1);
        float sn, cs;
        __sincosf((float)s * invf, &sn, &cs);
        float x0 = acc[i][0][reg]*qk_scale;
        float x1 = acc[i][1][reg]*qk_scale;
        u16* orow = out + ((size_t)(b*NH + head)*NS + s)*ND;
        orow[ 0 + l15] = f2bf(x0*cs - x1*sn);
        orow[16 + l15] = f2bf(x1*cs + x0*sn);
        orow[32 + l15] = f2bf(acc[i][2][reg]*qk_scale);
        orow[48 + l15] = f2bf(acc[i][3][reg]*qk_scale);
      }
    }
  }
}

// ---------------- Wo GEMM: fp32 out, flat grid 512, XCD-swizzled -----------
// Same 128^2 structure + same both-sides XOR swizzle.
__global__ __launch_bounds__(256)
void gemm_wo(const u16* __restrict__ A, const u16* __restrict__ Bt, float* __restrict__ out){
  __shared__ __align__(16) u16 As[128*64];
  __shared__ __align__(16) u16 Bs[128*64];
  const int gblk = blockIdx.x;
  const int wid = (gblk & 7) * 64 + (gblk >> 3);
  const int bx = wid & 7, by = wid >> 3;
  const int tid = threadIdx.x;
  const int lane = tid & 63, w = tid >> 6;
  const int wr = w >> 1, wc = w & 1;
  const int l15 = lane & 15, lhi = lane >> 4;
  const int brow = by * 128;
  const int bcol = bx * 128;
  const int K = NSTATE;
  f32x4 acc[4][4] = {};

  for (int kt = 0; kt < K; kt += 64){
    #pragma unroll
    for (int it = 0; it < 4; ++it){
      int flat = it*4096 + tid*16;
      int row = flat >> 7;
      int cb  = (flat >> 4) & 7;
      int scb = cb ^ (row & 7);
      gld_lds16(A + (size_t)(brow+row)*K + kt + scb*8, As + (flat>>1));
    }
    #pragma unroll
    for (int it = 0; it < 4; ++it){
      int flat = it*4096 + tid*16;
      int row = flat >> 7;
      int cb  = (flat >> 4) & 7;
      int scb = cb ^ (row & 7);
      gld_lds16(Bt + (size_t)(bcol+row)*K + kt + scb*8, Bs + (flat>>1));
    }
    __syncthreads();
    #pragma unroll
    for (int ks = 0; ks < 2; ++ks){
      short8 av[4], bv[4];
      #pragma unroll
      for (int i = 0; i < 4; ++i){
        int row = wr*64 + i*16 + l15;
        av[i] = *(const short8*)&As[row*64 + (((ks*4 + lhi) ^ (row & 7))*8)];
      }
      #pragma unroll
      for (int j = 0; j < 4; ++j){
        int row = wc*64 + j*16 + l15;
        bv[j] = *(const short8*)&Bs[row*64 + (((ks*4 + lhi) ^ (row & 7))*8)];
      }
      __builtin_amdgcn_s_setprio(1);
      #pragma unroll
      for (int i = 0; i < 4; ++i)
        #pragma unroll
        for (int j = 0; j < 4; ++j)
          acc[i][j] = mfma16x16(av[i], bv[j], acc[i][j]);
      __builtin_amdgcn_s_setprio(0);
    }
    __syncthreads();
  }
  #pragma unroll
  for (int i = 0; i < 4; ++i)
    #pragma unroll
    for (int reg = 0; reg < 4; ++reg){
      int m = brow + wr*64 + i*16 + lhi*4 + reg;
      float* orow = out + (size_t)m*NSTATE + bcol + wc*64;
      #pragma unroll
      for (int j = 0; j < 4; ++j)
        orow[j*16 + l15] = acc[i][j][reg];
    }
}

// ---------------- causal flash attention (32x32 swapped-QK, T12) ----------
// (unchanged from R9 -- session-best structure)
__global__ __launch_bounds__(256)
void flash_attn(const u16* __restrict__ Q, const u16* __restrict__ Kh,
                const u16* __restrict__ Vt, u16* __restrict__ O){
  __shared__ __align__(16) u16 Kbuf[2][64*64];
  __shared__ __align__(16) u16 Vbuf[2][64*64];
  const int gblk = blockIdx.x;
  const int xcd = gblk & 7, gr = gblk >> 3;     // 128 blocks per XCD
  const int bh  = xcd*8 + (gr & 7);             // 8 consecutive bh per XCD
  const int g   = 15 - (gr >> 3);               // long groups first
  const int tid = threadIdx.x;
  const int w = tid >> 6, lane = tid & 63;
  const int l31 = lane & 31, hi = lane >> 5;
  const u16* Qb = Q  + (size_t)bh*NS*ND;
  const u16* Kb = Kh + (size_t)bh*NS*ND;
  const u16* Vb = Vt + (size_t)bh*ND*NS;
  const int b = bh >> 4, h = bh & 15;
  const int qw = g*128 + w*32;
  const int kend_w   = qw + 32;
  const int kend_blk = g*128 + 128;

  short8 qf[4];
  #pragma unroll
  for (int dd = 0; dd < 4; ++dd)
    qf[dd] = *(const short8*)&Qb[(size_t)(qw + l31)*ND + dd*16 + hi*8];

  f32x16 oacc[2] = {};
  float mrun = 8.0f, lrun = 0.f;

  int cur = 0;
  #pragma unroll
  for (int i = 0; i < 2; ++i){
    int ch = i*256 + tid;
    int row = ch >> 3, cc = ch & 7;
    int scc = cc ^ (row & 7);
    gld_lds16(Kb + (size_t)row*ND + scc*8, &Kbuf[cur][ch*8]);
    gld_lds16(Vb + (size_t)row*NS + scc*8, &Vbuf[cur][ch*8]);
  }
  __syncthreads();

  #pragma unroll 1
  for (int kv0 = 0; kv0 < kend_blk; kv0 += 64){
    if (kv0 + 64 < kend_blk){
      #pragma unroll
      for (int i = 0; i < 2; ++i){
        int ch = i*256 + tid;
        int row = ch >> 3, cc = ch & 7;
        int scc = cc ^ (row & 7);
        gld_lds16(Kb + (size_t)(kv0 + 64 + row)*ND + scc*8, &Kbuf[cur^1][ch*8]);
        gld_lds16(Vb + (size_t)row*NS + kv0 + 64 + scc*8, &Vbuf[cur^1][ch*8]);
      }
    }
    if (kv0 < kend_w){
      const char* kb = (const char*)&Kbuf[cur][0];
      const char* vb = (const char*)&Vbuf[cur][0];
      short8 kf[8];
      #pragma unroll
      for (int kh2 = 0; kh2 < 2; ++kh2)
        #pragma unroll
        for (int dd = 0; dd < 4; ++dd){
          int srow = kh2*32 + l31;
          int off = (srow*128 + dd*32 + hi*16) ^ ((srow & 7) << 4);
          kf[kh2*4+dd] = *(const short8*)(kb + off);
        }
      f32x16 st0 = {}, st1 = {};
      __builtin_amdgcn_s_setprio(1);
      #pragma unroll
      for (int dd = 0; dd < 4; ++dd) st0 = mfma32(kf[dd],   qf[dd], st0);
      #pragma unroll
      for (int dd = 0; dd < 4; ++dd) st1 = mfma32(kf[4+dd], qf[dd], st1);
      __builtin_amdgcn_s_setprio(0);
      if (kv0 + 63 > qw){
        int q = qw + l31;
        #pragma unroll
        for (int r2 = 0; r2 < 16; ++r2){
          int k0 = kv0 + (r2 & 3) + 8*(r2 >> 2) + 4*hi;
          if (k0      > q) st0[r2] = -3.0e30f;
          if (k0 + 32 > q) st1[r2] = -3.0e30f;
        }
      }
      float m0 = fmaxf(fmaxf(st0[0], st0[1]), fmaxf(st0[2], st0[3]));
      float m1 = fmaxf(fmaxf(st0[4], st0[5]), fmaxf(st0[6], st0[7]));
      float m2 = fmaxf(fmaxf(st0[8], st0[9]), fmaxf(st0[10], st0[11]));
      float m3 = fmaxf(fmaxf(st0[12], st0[13]), fmaxf(st0[14], st0[15]));
      float m4 = fmaxf(fmaxf(st1[0], st1[1]), fmaxf(st1[2], st1[3]));
      float m5 = fmaxf(fmaxf(st1[4], st1[5]), fmaxf(st1[6], st1[7]));
      float m6 = fmaxf(fmaxf(st1[8], st1[9]), fmaxf(st1[10], st1[11]));
      float m7 = fmaxf(fmaxf(st1[12], st1[13]), fmaxf(st1[14], st1[15]));
      float pm = fmaxf(fmaxf(fmaxf(m0, m1), fmaxf(m2, m3)),
                       fmaxf(fmaxf(m4, m5), fmaxf(m6, m7)));
      pm = fmaxf(pm, __shfl_xor(pm, 32));
      #pragma unroll
      for (int r2 = 0; r2 < 16; ++r2){
        st0[r2] = EXP2(st0[r2] - mrun);
        st1[r2] = EXP2(st1[r2] - mrun);
      }
      float s0 = 0.f, s1 = 0.f, s2 = 0.f, s3 = 0.f;
      #pragma unroll
      for (int r2 = 0; r2 < 16; r2 += 4){
        s0 += st0[r2+0] + st1[r2+0];
        s1 += st0[r2+1] + st1[r2+1];
        s2 += st0[r2+2] + st1[r2+2];
        s3 += st0[r2+3] + st1[r2+3];
      }
      float rs = (s0 + s1) + (s2 + s3);
      rs += __shfl_xor(rs, 32);
      if (__any(pm > mrun)){
        float mn = fmaxf(mrun, pm);
        float a  = EXP2(mrun - mn);
        mrun = mn;
        lrun = (lrun + rs) * a;
        #pragma unroll
        for (int r2 = 0; r2 < 16; ++r2){
          st0[r2] *= a; st1[r2] *= a;
          oacc[0][r2] *= a; oacc[1][r2] *= a;
        }
      } else {
        lrun += rs;
      }
      short8 paf[4];
      #pragma unroll
      for (int sl = 0; sl < 4; ++sl){
        const f32x16& S = (sl < 2) ? st0 : st1;
        const int base = (sl & 1) * 8;
        u32 a0 = cvtpk(S[base+0], S[base+1]);
        u32 b0 = cvtpk(S[base+4], S[base+5]);
        asm("v_permlane32_swap_b32 %0, %1" : "+v"(a0), "+v"(b0));
        u32 a1 = cvtpk(S[base+2], S[base+3]);
        u32 b1 = cvtpk(S[base+6], S[base+7]);
        asm("v_permlane32_swap_b32 %0, %1" : "+v"(a1), "+v"(b1));
        union { u32 u[4]; short8 v; } pk_;
        pk_.u[0] = a0; pk_.u[1] = a1; pk_.u[2] = b0; pk_.u[3] = b1;
        paf[sl] = pk_.v;
      }
      #pragma unroll
      for (int dh = 0; dh < 2; ++dh){
        short8 vv[4];
        #pragma unroll
        for (int sl = 0; sl < 4; ++sl){
          int drow = dh*32 + l31;
          int off = (drow*128 + sl*32 + hi*16) ^ ((drow & 7) << 4);
          vv[sl] = *(const short8*)(vb + off);
        }
        __builtin_amdgcn_s_setprio(1);
        #pragma unroll
        for (int sl = 0; sl < 4; ++sl)
          oacc[dh] = mfma32(vv[sl], paf[sl], oacc[dh]);
        __builtin_amdgcn_s_setprio(0);
      }
    }
    __syncthreads();
    cur ^= 1;
  }

  float inv = 1.0f / lrun;
  u16* orow = O + ((size_t)(b*NS + qw + l31))*NSTATE + h*ND;
  #pragma unroll
  for (int dh = 0; dh < 2; ++dh)
    #pragma unroll
    for (int rq = 0; rq < 4; ++rq){
      uint2 pk;
      pk.x = cvtpk(oacc[dh][rq*4+0]*inv, oacc[dh][rq*4+1]*inv);
      pk.y = cvtpk(oacc[dh][rq*4+2]*inv, oacc[dh][rq*4+3]*inv);
      *(uint2*)(orow + dh*32 + rq*8 + hi*4) = pk;
    }
}

// ---------------------------------------------------------------------------
extern "C" void kernel_launch(void* const* d_in, const int* in_sizes, int n_in,
                              void* d_out, int out_size, void* d_ws, size_t ws_size,
                              hipStream_t stream){
  const float* q_src = (const float*)d_in[0];
  const float* k_src = (const float*)d_in[1];
  const float* v_src = (const float*)d_in[2];
  // d_in[3] = position_mask (causal, statically known) — unused
  const float* Wq = (const float*)d_in[4];
  const float* Wk = (const float*)d_in[5];
  const float* Wv = (const float*)d_in[6];
  const float* Wo = (const float*)d_in[7];

  char* ws = (char*)d_ws;
  const size_t MB = 1u << 20;
  if (ws_size < 104*MB) return;   // need 104 MB of scratch

  u16* xq   = (u16*)(ws +  0*MB);   // 16 MB  (bf16 q_src)
  u16* xk   = (u16*)(ws + 16*MB);   // 16 MB  (bf16 k_src)   -> reused as attn out
  u16* xv   = (u16*)(ws + 32*MB);   // 16 MB  (bf16 v_src)
  u16* wq16 = (u16*)(ws + 48*MB);   //  2 MB  } contiguous => Wcat [3072][1024]
  u16* wk16 = (u16*)(ws + 50*MB);   //  2 MB  }
  u16* wv16 = (u16*)(ws + 52*MB);   //  2 MB  }
  u16* wo16 = (u16*)(ws + 54*MB);   //  2 MB
  u16* Qh   = (u16*)(ws + 56*MB);   // 16 MB  [B,H,S,D]
  u16* Kk   = (u16*)(ws + 72*MB);   // 16 MB  [B,H,S,D]
  u16* Vt   = (u16*)(ws + 88*MB);   // 16 MB  [B,H,D,S]  (direct from gemm_qkv)
  u16* Oat  = xk;                   // [B,S,H*D]  (xk dead after QKV gemm)

  cvt_all<<<dim3(28672), dim3(256), 0, stream>>>(q_src, k_src, v_src, Wq, Wk, Wv, Wo,
                                                 xq, xk, xv, wq16, wk16, wv16, wo16);
  gemm_qkv<<<dim3(1536), dim3(256), 0, stream>>>(xq, xk, xv, wq16, Qh, Kk, Vt);
  flash_attn<<<dim3(1024), dim3(256), 0, stream>>>(Qh, Kk, Vt, Oat);
  gemm_wo<<<dim3(512), dim3(256), 0, stream>>>(Oat, wo16, (float*)d_out);
}

// Round 12
// 192.671 us; speedup vs baseline: 1.1625x; 1.0191x over previous
//
#include <hip/hip_runtime.h>

typedef unsigned short u16;
typedef unsigned int u32;
typedef short short8 __attribute__((ext_vector_type(8)));
typedef float f32x4 __attribute__((ext_vector_type(4)));
typedef float f32x16 __attribute__((ext_vector_type(16)));

#define NB 4
#define NS 2048
#define NSTATE 1024
#define NH 16
#define ND 64
#define NM (NB*NS)   // 8192 rows

#if __has_builtin(__builtin_amdgcn_exp2f)
#define EXP2(x) __builtin_amdgcn_exp2f(x)
#else
#define EXP2(x) __expf((x) * 0.6931471805599453f)
#endif

__device__ __forceinline__ u16 f2bf(float f){
  union { float fv; unsigned uv; } x; x.fv = f;
  unsigned r = x.uv + 0x7fffu + ((x.uv >> 16) & 1u);
  return (u16)(r >> 16);
}

__device__ __forceinline__ u32 cvtpk(float lo, float hi){
  u32 r;
  asm("v_cvt_pk_bf16_f32 %0, %1, %2" : "=v"(r) : "v"(lo), "v"(hi));
  return r;
}

__device__ __forceinline__ float max3f(float a, float b, float c){
  return fmaxf(fmaxf(a, b), c);     // clang fuses to v_max3_f32
}

__device__ __forceinline__ f32x4 mfma16x16(short8 a, short8 b, f32x4 c){
  return __builtin_amdgcn_mfma_f32_16x16x32_bf16(a, b, c, 0, 0, 0);
}

__device__ __forceinline__ f32x16 mfma32(short8 a, short8 b, f32x16 c){
  return __builtin_amdgcn_mfma_f32_32x32x16_bf16(a, b, c, 0, 0, 0);
}

__device__ __forceinline__ void gld_lds16(const u16* g, u16* l){
  __builtin_amdgcn_global_load_lds((const __attribute__((address_space(1))) void*)g,
                                   (__attribute__((address_space(3))) void*)l, 16, 0, 0);
}

// ---------------- fp32 -> bf16 conversion for 3 activations + 4 weights ----
__global__ __launch_bounds__(256)
void cvt_all(const float* __restrict__ q, const float* __restrict__ k, const float* __restrict__ v,
             const float* __restrict__ wq, const float* __restrict__ wk,
             const float* __restrict__ wv, const float* __restrict__ wo,
             u16* oq, u16* ok, u16* ov, u16* owq, u16* owk, u16* owv, u16* owo){
  const int XN4 = (NB*NS*NSTATE)/4;   // 2097152
  const int WN4 = (NSTATE*NSTATE)/4;  // 262144
  int gid = blockIdx.x * 256 + threadIdx.x;
  const float* src; u16* dst; int idx;
  if (gid < XN4)          { src = q; dst = oq; idx = gid; }
  else if (gid < 2*XN4)   { src = k; dst = ok; idx = gid - XN4; }
  else if (gid < 3*XN4)   { src = v; dst = ov; idx = gid - 2*XN4; }
  else {
    int g = gid - 3*XN4;
    int wsel = g >> 18;       // / WN4
    idx = g & (WN4 - 1);
    src = (wsel==0)?wq:(wsel==1)?wk:(wsel==2)?wv:wo;
    dst = (wsel==0)?owq:(wsel==1)?owk:(wsel==2)?owv:owo;
  }
  float4 val = ((const float4*)src)[idx];
  ushort4 r;
  r.x = f2bf(val.x); r.y = f2bf(val.y); r.z = f2bf(val.z); r.w = f2bf(val.w);
  ((ushort4*)dst)[idx] = r;
}

// ---------------- merged QKV projection GEMM (128^2 + XOR swizzle) --------
__global__ __launch_bounds__(256)
void gemm_qkv(const u16* __restrict__ xq, const u16* __restrict__ xk,
              const u16* __restrict__ xv, const u16* __restrict__ Wcat,
              u16* __restrict__ Qh, u16* __restrict__ Kk, u16* __restrict__ Vt){
  __shared__ __align__(16) u16 As[128*64];
  __shared__ __align__(16) u16 Bs[128*64];
  const int gblk = blockIdx.x;
  const int wid = (gblk & 7) * 192 + (gblk >> 3);
  const int bx = wid % 24, by = wid / 24;
  const int sel = bx >> 3;                        // 0=Q 1=K 2=V
  const u16* A = (sel==0) ? xq : (sel==1) ? xk : xv;
  const int tid = threadIdx.x;
  const int lane = tid & 63, w = tid >> 6;
  const int wr = w >> 1, wc = w & 1;
  const int l15 = lane & 15, lhi = lane >> 4;
  const int brow = by * 128;
  const int bcol = bx * 128;                      // global col in [0,3072)
  const int K = NSTATE;
  f32x4 acc[4][4] = {};

  for (int kt = 0; kt < K; kt += 64){
    #pragma unroll
    for (int it = 0; it < 4; ++it){               // stage A tile 128x64
      int flat = it*4096 + tid*16;                // byte index in tile
      int row = flat >> 7;
      int cb  = (flat >> 4) & 7;                  // 16B chunk in row
      int scb = cb ^ (row & 7);                   // inverse-swizzled source
      gld_lds16(A + (size_t)(brow+row)*K + kt + scb*8, As + (flat>>1));
    }
    #pragma unroll
    for (int it = 0; it < 4; ++it){               // stage B tile 128x64
      int flat = it*4096 + tid*16;
      int row = flat >> 7;
      int cb  = (flat >> 4) & 7;
      int scb = cb ^ (row & 7);
      gld_lds16(Wcat + (size_t)(bcol+row)*K + kt + scb*8, Bs + (flat>>1));
    }
    __syncthreads();
    #pragma unroll
    for (int ks = 0; ks < 2; ++ks){
      short8 av[4], bv[4];
      #pragma unroll
      for (int i = 0; i < 4; ++i){
        int row = wr*64 + i*16 + l15;
        av[i] = *(const short8*)&As[row*64 + (((ks*4 + lhi) ^ (row & 7))*8)];
      }
      #pragma unroll
      for (int j = 0; j < 4; ++j){
        int row = wc*64 + j*16 + l15;
        bv[j] = *(const short8*)&Bs[row*64 + (((ks*4 + lhi) ^ (row & 7))*8)];
      }
      __builtin_amdgcn_s_setprio(1);
      #pragma unroll
      for (int i = 0; i < 4; ++i)
        #pragma unroll
        for (int j = 0; j < 4; ++j)
          acc[i][j] = mfma16x16(av[i], bv[j], acc[i][j]);
      __builtin_amdgcn_s_setprio(0);
    }
    __syncthreads();
  }

  const int col0 = bcol + wc*64;                  // wave's 64-col slab (one head)
  if (sel == 2){
    // V -> Vt[B,H,D,S] directly: d = j*16+l15, s0 = (m of reg 0) & 2047.
    const int head = (col0 & 1023) >> 6;
    #pragma unroll
    for (int i = 0; i < 4; ++i){
      int m0 = brow + wr*64 + i*16 + lhi*4;       // reg 0 row (4 consecutive s)
      int b = m0 >> 11, s0 = m0 & (NS-1);
      u16* obase = Vt + ((size_t)((b*NH + head)*ND))*NS + s0;
      #pragma unroll
      for (int j = 0; j < 4; ++j){
        int d = j*16 + l15;
        uint2 pk;
        pk.x = cvtpk(acc[i][j][0], acc[i][j][1]);
        pk.y = cvtpk(acc[i][j][2], acc[i][j][3]);
        *(uint2*)(obase + (size_t)d*NS) = pk;
      }
    }
  } else {
    // Q/K: scale (incl sqrt(log2e)) + RoPE, write [B,H,S,D]
    u16* out = sel ? Kk : Qh;
    const float qk_scale = 0.4246609f;            // (1/8)^0.5 * sqrt(log2 e)
    const int head = (col0 & 1023) >> 6;
    const float invf = EXP2(-0.83048202f * (float)l15);   // 10000^(-l15/16)
    #pragma unroll
    for (int i = 0; i < 4; ++i){
      #pragma unroll
      for (int reg = 0; reg < 4; ++reg){
        int m = brow + wr*64 + i*16 + lhi*4 + reg;
        int b = m >> 11, s = m & (NS-1);
        float sn, cs;
        __sincosf((float)s * invf, &sn, &cs);
        float x0 = acc[i][0][reg]*qk_scale;
        float x1 = acc[i][1][reg]*qk_scale;
        u16* orow = out + ((size_t)(b*NH + head)*NS + s)*ND;
        orow[ 0 + l15] = f2bf(x0*cs - x1*sn);
        orow[16 + l15] = f2bf(x1*cs + x0*sn);
        orow[32 + l15] = f2bf(acc[i][2][reg]*qk_scale);
        orow[48 + l15] = f2bf(acc[i][3][reg]*qk_scale);
      }
    }
  }
}

// ---------------- Wo GEMM: fp32 out, flat grid 512, XCD-swizzled -----------
__global__ __launch_bounds__(256)
void gemm_wo(const u16* __restrict__ A, const u16* __restrict__ Bt, float* __restrict__ out){
  __shared__ __align__(16) u16 As[128*64];
  __shared__ __align__(16) u16 Bs[128*64];
  const int gblk = blockIdx.x;
  const int wid = (gblk & 7) * 64 + (gblk >> 3);
  const int bx = wid & 7, by = wid >> 3;
  const int tid = threadIdx.x;
  const int lane = tid & 63, w = tid >> 6;
  const int wr = w >> 1, wc = w & 1;
  const int l15 = lane & 15, lhi = lane >> 4;
  const int brow = by * 128;
  const int bcol = bx * 128;
  const int K = NSTATE;
  f32x4 acc[4][4] = {};

  for (int kt = 0; kt < K; kt += 64){
    #pragma unroll
    for (int it = 0; it < 4; ++it){
      int flat = it*4096 + tid*16;
      int row = flat >> 7;
      int cb  = (flat >> 4) & 7;
      int scb = cb ^ (row & 7);
      gld_lds16(A + (size_t)(brow+row)*K + kt + scb*8, As + (flat>>1));
    }
    #pragma unroll
    for (int it = 0; it < 4; ++it){
      int flat = it*4096 + tid*16;
      int row = flat >> 7;
      int cb  = (flat >> 4) & 7;
      int scb = cb ^ (row & 7);
      gld_lds16(Bt + (size_t)(bcol+row)*K + kt + scb*8, Bs + (flat>>1));
    }
    __syncthreads();
    #pragma unroll
    for (int ks = 0; ks < 2; ++ks){
      short8 av[4], bv[4];
      #pragma unroll
      for (int i = 0; i < 4; ++i){
        int row = wr*64 + i*16 + l15;
        av[i] = *(const short8*)&As[row*64 + (((ks*4 + lhi) ^ (row & 7))*8)];
      }
      #pragma unroll
      for (int j = 0; j < 4; ++j){
        int row = wc*64 + j*16 + l15;
        bv[j] = *(const short8*)&Bs[row*64 + (((ks*4 + lhi) ^ (row & 7))*8)];
      }
      __builtin_amdgcn_s_setprio(1);
      #pragma unroll
      for (int i = 0; i < 4; ++i)
        #pragma unroll
        for (int j = 0; j < 4; ++j)
          acc[i][j] = mfma16x16(av[i], bv[j], acc[i][j]);
      __builtin_amdgcn_s_setprio(0);
    }
    __syncthreads();
  }
  #pragma unroll
  for (int i = 0; i < 4; ++i)
    #pragma unroll
    for (int reg = 0; reg < 4; ++reg){
      int m = brow + wr*64 + i*16 + lhi*4 + reg;
      float* orow = out + (size_t)m*NSTATE + bcol + wc*64;
      #pragma unroll
      for (int j = 0; j < 4; ++j)
        orow[j*16 + l15] = acc[i][j][reg];
    }
}

// ---------------- causal flash attention (32x32 swapped-QK, paired) -------
// 256-thread blocks (4 waves), grid 512. Block handles group pair (c, 15-c)
// sequentially -> every block exactly 34 kv-iters (perfect balance, no
// occupancy-decay tail: R11 measured 19% avg occupancy from unequal blocks).
// XCD swizzle (8 bh per XCD). K/V double-buffered in LDS (global_load_lds,
// both-sides XOR swizzle). Lane owns q=lane&31 (swapped QK^T). Row-sum via
// ones-MFMA: lacc = mfma32(ones, paf, lacc) -> replaces ~31 VALU adds +
// shfl per iter, carries the denominator across iters (fixup just scales).
// mrun = 12 (row maxes ~<=11 -> fixup ~never fires; exact path retained).
__global__ __launch_bounds__(256)
void flash_attn(const u16* __restrict__ Q, const u16* __restrict__ Kh,
                const u16* __restrict__ Vt, u16* __restrict__ O){
  __shared__ __align__(16) u16 Kbuf[2][64*64];
  __shared__ __align__(16) u16 Vbuf[2][64*64];
  const int gblk = blockIdx.x;
  const int xcd = gblk & 7, gr = gblk >> 3;     // 64 blocks per XCD
  const int bh  = xcd*8 + (gr & 7);             // 8 consecutive bh per XCD
  const int c   = gr >> 3;                      // pair index 0..7
  const int tid = threadIdx.x;
  const int w = tid >> 6, lane = tid & 63;
  const int l31 = lane & 31, hi = lane >> 5;
  const u16* Qb = Q  + (size_t)bh*NS*ND;
  const u16* Kb = Kh + (size_t)bh*NS*ND;
  const u16* Vb = Vt + (size_t)bh*ND*NS;
  const int b = bh >> 4, h = bh & 15;

  short8 ones;
  #pragma unroll
  for (int i = 0; i < 8; ++i) ones[i] = (short)0x3F80;   // bf16 1.0

  #pragma unroll 1
  for (int ph = 0; ph < 2; ++ph){
    const int g  = ph ? (15 - c) : c;
    const int qw = g*128 + w*32;
    const int kend_w   = qw + 32;
    const int kend_blk = g*128 + 128;

    short8 qf[4];
    #pragma unroll
    for (int dd = 0; dd < 4; ++dd)
      qf[dd] = *(const short8*)&Qb[(size_t)(qw + l31)*ND + dd*16 + hi*8];

    f32x16 oacc[2] = {};
    f32x16 lacc = {};
    float mrun = 12.0f;

    int cur = 0;
    #pragma unroll
    for (int i = 0; i < 2; ++i){
      int ch = i*256 + tid;
      int row = ch >> 3, cc = ch & 7;
      int scc = cc ^ (row & 7);
      gld_lds16(Kb + (size_t)row*ND + scc*8, &Kbuf[cur][ch*8]);
      gld_lds16(Vb + (size_t)row*NS + scc*8, &Vbuf[cur][ch*8]);
    }
    __syncthreads();

    #pragma unroll 1
    for (int kv0 = 0; kv0 < kend_blk; kv0 += 64){
      if (kv0 + 64 < kend_blk){
        #pragma unroll
        for (int i = 0; i < 2; ++i){
          int ch = i*256 + tid;
          int row = ch >> 3, cc = ch & 7;
          int scc = cc ^ (row & 7);
          gld_lds16(Kb + (size_t)(kv0 + 64 + row)*ND + scc*8, &Kbuf[cur^1][ch*8]);
          gld_lds16(Vb + (size_t)row*NS + kv0 + 64 + scc*8, &Vbuf[cur^1][ch*8]);
        }
      }
      if (kv0 < kend_w){
        const char* kb = (const char*)&Kbuf[cur][0];
        const char* vb = (const char*)&Vbuf[cur][0];
        short8 kf[8];
        #pragma unroll
        for (int kh2 = 0; kh2 < 2; ++kh2)
          #pragma unroll
          for (int dd = 0; dd < 4; ++dd){
            int srow = kh2*32 + l31;
            int off = (srow*128 + dd*32 + hi*16) ^ ((srow & 7) << 4);
            kf[kh2*4+dd] = *(const short8*)(kb + off);
          }
        f32x16 st0 = {}, st1 = {};
        __builtin_amdgcn_s_setprio(1);
        #pragma unroll
        for (int dd = 0; dd < 4; ++dd) st0 = mfma32(kf[dd],   qf[dd], st0);
        #pragma unroll
        for (int dd = 0; dd < 4; ++dd) st1 = mfma32(kf[4+dd], qf[dd], st1);
        __builtin_amdgcn_s_setprio(0);
        // causal mask (diagonal blocks only)
        if (kv0 + 63 > qw){
          int q = qw + l31;
          #pragma unroll
          for (int r2 = 0; r2 < 16; ++r2){
            int k0 = kv0 + (r2 & 3) + 8*(r2 >> 2) + 4*hi;
            if (k0      > q) st0[r2] = -3.0e30f;
            if (k0 + 32 > q) st1[r2] = -3.0e30f;
          }
        }
        // row max via max3 trees (lane-local + partner shfl)
        float t0 = max3f(st0[0],  st0[1],  st0[2]);
        float t1 = max3f(st0[3],  st0[4],  st0[5]);
        float t2 = max3f(st0[6],  st0[7],  st0[8]);
        float t3 = max3f(st0[9],  st0[10], st0[11]);
        float t4 = max3f(st0[12], st0[13], st0[14]);
        float t5 = max3f(st1[0],  st1[1],  st1[2]);
        float t6 = max3f(st1[3],  st1[4],  st1[5]);
        float t7 = max3f(st1[6],  st1[7],  st1[8]);
        float t8 = max3f(st1[9],  st1[10], st1[11]);
        float t9 = max3f(st1[12], st1[13], st1[14]);
        float u0 = max3f(t0, t1, t2);
        float u1 = max3f(t3, t4, st0[15]);
        float u2 = max3f(t5, t6, t7);
        float u3 = max3f(t8, t9, st1[15]);
        float pm = fmaxf(max3f(u0, u1, u2), u3);
        pm = fmaxf(pm, __shfl_xor(pm, 32));
        // speculative P = exp2(S - mrun)
        #pragma unroll
        for (int r2 = 0; r2 < 16; ++r2){
          st0[r2] = EXP2(st0[r2] - mrun);
          st1[r2] = EXP2(st1[r2] - mrun);
        }
        // rare exact fixup (lane-local)
        if (__any(pm > mrun)){
          float mn = fmaxf(mrun, pm);
          float a  = EXP2(mrun - mn);
          mrun = mn;
          #pragma unroll
          for (int r2 = 0; r2 < 16; ++r2){
            st0[r2] *= a; st1[r2] *= a;
            oacc[0][r2] *= a; oacc[1][r2] *= a;
            lacc[r2] *= a;
          }
        }
        // pack P -> PV B-fragments in-register (cvt_pk + permlane32_swap)
        short8 paf[4];
        #pragma unroll
        for (int sl = 0; sl < 4; ++sl){
          const f32x16& S = (sl < 2) ? st0 : st1;
          const int base = (sl & 1) * 8;
          u32 a0 = cvtpk(S[base+0], S[base+1]);
          u32 b0 = cvtpk(S[base+4], S[base+5]);
          asm("v_permlane32_swap_b32 %0, %1" : "+v"(a0), "+v"(b0));
          u32 a1 = cvtpk(S[base+2], S[base+3]);
          u32 b1 = cvtpk(S[base+6], S[base+7]);
          asm("v_permlane32_swap_b32 %0, %1" : "+v"(a1), "+v"(b1));
          union { u32 u[4]; short8 v; } pk_;
          pk_.u[0] = a0; pk_.u[1] = a1; pk_.u[2] = b0; pk_.u[3] = b1;
          paf[sl] = pk_.v;
        }
        // O^T += V^T . P ; denominator via ones-MFMA (all rows = full k-sum)
        #pragma unroll
        for (int dh = 0; dh < 2; ++dh){
          short8 vv[4];
          #pragma unroll
          for (int sl = 0; sl < 4; ++sl){
            int drow = dh*32 + l31;
            int off = (drow*128 + sl*32 + hi*16) ^ ((drow & 7) << 4);
            vv[sl] = *(const short8*)(vb + off);
          }
          __builtin_amdgcn_s_setprio(1);
          #pragma unroll
          for (int sl = 0; sl < 4; ++sl)
            oacc[dh] = mfma32(vv[sl], paf[sl], oacc[dh]);
          __builtin_amdgcn_s_setprio(0);
        }
        __builtin_amdgcn_s_setprio(1);
        #pragma unroll
        for (int sl = 0; sl < 4; ++sl)
          lacc = mfma32(ones, paf[sl], lacc);
        __builtin_amdgcn_s_setprio(0);
      }
      __syncthreads();
      cur ^= 1;
    }

    // epilogue: O[q][d] = oacc/l ; l = lacc[0] (rows identical by A=ones)
    float inv = 1.0f / lacc[0];
    u16* orow = O + ((size_t)(b*NS + qw + l31))*NSTATE + h*ND;
    #pragma unroll
    for (int dh = 0; dh < 2; ++dh)
      #pragma unroll
      for (int rq = 0; rq < 4; ++rq){
        uint2 pk;
        pk.x = cvtpk(oacc[dh][rq*4+0]*inv, oacc[dh][rq*4+1]*inv);
        pk.y = cvtpk(oacc[dh][rq*4+2]*inv, oacc[dh][rq*4+3]*inv);
        *(uint2*)(orow + dh*32 + rq*8 + hi*4) = pk;
      }
  }
}

// ---------------------------------------------------------------------------
extern "C" void kernel_launch(void* const* d_in, const int* in_sizes, int n_in,
                              void* d_out, int out_size, void* d_ws, size_t ws_size,
                              hipStream_t stream){
  const float* q_src = (const float*)d_in[0];
  const float* k_src = (const float*)d_in[1];
  const float* v_src = (const float*)d_in[2];
  // d_in[3] = position_mask (causal, statically known) — unused
  const float* Wq = (const float*)d_in[4];
  const float* Wk = (const float*)d_in[5];
  const float* Wv = (const float*)d_in[6];
  const float* Wo = (const float*)d_in[7];

  char* ws = (char*)d_ws;
  const size_t MB = 1u << 20;
  if (ws_size < 104*MB) return;   // need 104 MB of scratch

  u16* xq   = (u16*)(ws +  0*MB);   // 16 MB  (bf16 q_src)
  u16* xk   = (u16*)(ws + 16*MB);   // 16 MB  (bf16 k_src)   -> reused as attn out
  u16* xv   = (u16*)(ws + 32*MB);   // 16 MB  (bf16 v_src)
  u16* wq16 = (u16*)(ws + 48*MB);   //  2 MB  } contiguous => Wcat [3072][1024]
  u16* wk16 = (u16*)(ws + 50*MB);   //  2 MB  }
  u16* wv16 = (u16*)(ws + 52*MB);   //  2 MB  }
  u16* wo16 = (u16*)(ws + 54*MB);   //  2 MB
  u16* Qh   = (u16*)(ws + 56*MB);   // 16 MB  [B,H,S,D]
  u16* Kk   = (u16*)(ws + 72*MB);   // 16 MB  [B,H,S,D]
  u16* Vt   = (u16*)(ws + 88*MB);   // 16 MB  [B,H,D,S]  (direct from gemm_qkv)
  u16* Oat  = xk;                   // [B,S,H*D]  (xk dead after QKV gemm)

  cvt_all<<<dim3(28672), dim3(256), 0, stream>>>(q_src, k_src, v_src, Wq, Wk, Wv, Wo,
                                                 xq, xk, xv, wq16, wk16, wv16, wo16);
  gemm_qkv<<<dim3(1536), dim3(256), 0, stream>>>(xq, xk, xv, wq16, Qh, Kk, Vt);
  flash_attn<<<dim3(512), dim3(256), 0, stream>>>(Qh, Kk, Vt, Oat);
  gemm_wo<<<dim3(512), dim3(256), 0, stream>>>(Oat, wo16, (float*)d_out);
}

// Round 13
// 189.469 us; speedup vs baseline: 1.1822x; 1.0169x over previous
//
#include <hip/hip_runtime.h>

typedef unsigned short u16;
typedef unsigned int u32;
typedef short short8 __attribute__((ext_vector_type(8)));
typedef float f32x4 __attribute__((ext_vector_type(4)));
typedef float f32x16 __attribute__((ext_vector_type(16)));

#define NB 4
#define NS 2048
#define NSTATE 1024
#define NH 16
#define ND 64
#define NM (NB*NS)   // 8192 rows

#if __has_builtin(__builtin_amdgcn_exp2f)
#define EXP2(x) __builtin_amdgcn_exp2f(x)
#else
#define EXP2(x) __expf((x) * 0.6931471805599453f)
#endif

__device__ __forceinline__ u16 f2bf(float f){
  union { float fv; unsigned uv; } x; x.fv = f;
  unsigned r = x.uv + 0x7fffu + ((x.uv >> 16) & 1u);
  return (u16)(r >> 16);
}

__device__ __forceinline__ u32 cvtpk(float lo, float hi){
  u32 r;
  asm("v_cvt_pk_bf16_f32 %0, %1, %2" : "=v"(r) : "v"(lo), "v"(hi));
  return r;
}

__device__ __forceinline__ float max3f(float a, float b, float c){
  return fmaxf(fmaxf(a, b), c);     // clang fuses to v_max3_f32
}

__device__ __forceinline__ f32x4 mfma16x16(short8 a, short8 b, f32x4 c){
  return __builtin_amdgcn_mfma_f32_16x16x32_bf16(a, b, c, 0, 0, 0);
}

__device__ __forceinline__ f32x16 mfma32(short8 a, short8 b, f32x16 c){
  return __builtin_amdgcn_mfma_f32_32x32x16_bf16(a, b, c, 0, 0, 0);
}

__device__ __forceinline__ void gld_lds16(const u16* g, u16* l){
  __builtin_amdgcn_global_load_lds((const __attribute__((address_space(1))) void*)g,
                                   (__attribute__((address_space(3))) void*)l, 16, 0, 0);
}

// ---------------- fp32 -> bf16 conversion for 3 activations + 4 weights ----
__global__ __launch_bounds__(256)
void cvt_all(const float* __restrict__ q, const float* __restrict__ k, const float* __restrict__ v,
             const float* __restrict__ wq, const float* __restrict__ wk,
             const float* __restrict__ wv, const float* __restrict__ wo,
             u16* oq, u16* ok, u16* ov, u16* owq, u16* owk, u16* owv, u16* owo){
  const int XN4 = (NB*NS*NSTATE)/4;   // 2097152
  const int WN4 = (NSTATE*NSTATE)/4;  // 262144
  int gid = blockIdx.x * 256 + threadIdx.x;
  const float* src; u16* dst; int idx;
  if (gid < XN4)          { src = q; dst = oq; idx = gid; }
  else if (gid < 2*XN4)   { src = k; dst = ok; idx = gid - XN4; }
  else if (gid < 3*XN4)   { src = v; dst = ov; idx = gid - 2*XN4; }
  else {
    int g = gid - 3*XN4;
    int wsel = g >> 18;       // / WN4
    idx = g & (WN4 - 1);
    src = (wsel==0)?wq:(wsel==1)?wk:(wsel==2)?wv:wo;
    dst = (wsel==0)?owq:(wsel==1)?owk:(wsel==2)?owv:owo;
  }
  float4 val = ((const float4*)src)[idx];
  ushort4 r;
  r.x = f2bf(val.x); r.y = f2bf(val.y); r.z = f2bf(val.z); r.w = f2bf(val.w);
  ((ushort4*)dst)[idx] = r;
}

// ---------------- merged QKV projection GEMM (128^2 + swizzle + hoisted) --
// All address arithmetic hoisted out of the K loop: staging offsets are
// affine in kt (32-bit offsets, +kt per iter); fragment offsets are
// kt-invariant, with the ks=1 slot derived by ^32 elements (XOR linearity
// of the swizzle). Inner loop = 8 gld_lds16 + 16 ds_read_b128 + 32 MFMA.
__global__ __launch_bounds__(256)
void gemm_qkv(const u16* __restrict__ xq, const u16* __restrict__ xk,
              const u16* __restrict__ xv, const u16* __restrict__ Wcat,
              u16* __restrict__ Qh, u16* __restrict__ Kk, u16* __restrict__ Vt){
  __shared__ __align__(16) u16 As[128*64];
  __shared__ __align__(16) u16 Bs[128*64];
  const int gblk = blockIdx.x;
  const int wid = (gblk & 7) * 192 + (gblk >> 3);
  const int bx = wid % 24, by = wid / 24;
  const int sel = bx >> 3;                        // 0=Q 1=K 2=V
  const u16* A = (sel==0) ? xq : (sel==1) ? xk : xv;
  const int tid = threadIdx.x;
  const int lane = tid & 63, w = tid >> 6;
  const int wr = w >> 1, wc = w & 1;
  const int l15 = lane & 15, lhi = lane >> 4;
  const int brow = by * 128;
  const int bcol = bx * 128;                      // global col in [0,3072)
  const int K = NSTATE;
  f32x4 acc[4][4] = {};

  // hoisted staging offsets: row = it*32 + tid>>3, chunk = (tid&7)^(row&7)
  int aoffg[4], boffg[4];
  {
    int r0 = tid >> 3;
    int scb = (tid & 7) ^ (r0 & 7);
    #pragma unroll
    for (int it = 0; it < 4; ++it){
      int row = it*32 + r0;
      aoffg[it] = (brow + row)*K + scb*8;
      boffg[it] = (bcol + row)*K + scb*8;
    }
  }
  // hoisted fragment offsets (ks=0 slot; ks=1 = ^32 elements)
  int afr[4], bfr[4];
  #pragma unroll
  for (int i = 0; i < 4; ++i){
    int rowA = wr*64 + i*16 + l15;
    afr[i] = rowA*64 + ((lhi ^ (rowA & 7))*8);
    int rowB = wc*64 + i*16 + l15;
    bfr[i] = rowB*64 + ((lhi ^ (rowB & 7))*8);
  }

  for (int kt = 0; kt < K; kt += 64){
    #pragma unroll
    for (int it = 0; it < 4; ++it)
      gld_lds16(A + aoffg[it] + kt, As + it*2048 + tid*8);
    #pragma unroll
    for (int it = 0; it < 4; ++it)
      gld_lds16(Wcat + boffg[it] + kt, Bs + it*2048 + tid*8);
    __syncthreads();
    #pragma unroll
    for (int ks = 0; ks < 2; ++ks){
      short8 av[4], bv[4];
      #pragma unroll
      for (int i = 0; i < 4; ++i)
        av[i] = *(const short8*)&As[afr[i] ^ (ks << 5)];
      #pragma unroll
      for (int j = 0; j < 4; ++j)
        bv[j] = *(const short8*)&Bs[bfr[j] ^ (ks << 5)];
      __builtin_amdgcn_s_setprio(1);
      #pragma unroll
      for (int i = 0; i < 4; ++i)
        #pragma unroll
        for (int j = 0; j < 4; ++j)
          acc[i][j] = mfma16x16(av[i], bv[j], acc[i][j]);
      __builtin_amdgcn_s_setprio(0);
    }
    __syncthreads();
  }

  const int col0 = bcol + wc*64;                  // wave's 64-col slab (one head)
  if (sel == 2){
    // V -> Vt[B,H,D,S] directly: d = j*16+l15, s0 = (m of reg 0) & 2047.
    const int head = (col0 & 1023) >> 6;
    #pragma unroll
    for (int i = 0; i < 4; ++i){
      int m0 = brow + wr*64 + i*16 + lhi*4;       // reg 0 row (4 consecutive s)
      int b = m0 >> 11, s0 = m0 & (NS-1);
      u16* obase = Vt + ((size_t)((b*NH + head)*ND))*NS + s0;
      #pragma unroll
      for (int j = 0; j < 4; ++j){
        int d = j*16 + l15;
        uint2 pk;
        pk.x = cvtpk(acc[i][j][0], acc[i][j][1]);
        pk.y = cvtpk(acc[i][j][2], acc[i][j][3]);
        *(uint2*)(obase + (size_t)d*NS) = pk;
      }
    }
  } else {
    // Q/K: scale (incl sqrt(log2e)) + RoPE, write [B,H,S,D]
    u16* out = sel ? Kk : Qh;
    const float qk_scale = 0.4246609f;            // (1/8)^0.5 * sqrt(log2 e)
    const int head = (col0 & 1023) >> 6;
    const float invf = EXP2(-0.83048202f * (float)l15);   // 10000^(-l15/16)
    #pragma unroll
    for (int i = 0; i < 4; ++i){
      #pragma unroll
      for (int reg = 0; reg < 4; ++reg){
        int m = brow + wr*64 + i*16 + lhi*4 + reg;
        int b = m >> 11, s = m & (NS-1);
        float sn, cs;
        __sincosf((float)s * invf, &sn, &cs);
        float x0 = acc[i][0][reg]*qk_scale;
        float x1 = acc[i][1][reg]*qk_scale;
        u16* orow = out + ((size_t)(b*NH + head)*NS + s)*ND;
        orow[ 0 + l15] = f2bf(x0*cs - x1*sn);
        orow[16 + l15] = f2bf(x1*cs + x0*sn);
        orow[32 + l15] = f2bf(acc[i][2][reg]*qk_scale);
        orow[48 + l15] = f2bf(acc[i][3][reg]*qk_scale);
      }
    }
  }
}

// ---------------- Wo GEMM: fp32 out, flat grid 512, XCD-swizzled ----------
// Same hoisted-address structure.
__global__ __launch_bounds__(256)
void gemm_wo(const u16* __restrict__ A, const u16* __restrict__ Bt, float* __restrict__ out){
  __shared__ __align__(16) u16 As[128*64];
  __shared__ __align__(16) u16 Bs[128*64];
  const int gblk = blockIdx.x;
  const int wid = (gblk & 7) * 64 + (gblk >> 3);
  const int bx = wid & 7, by = wid >> 3;
  const int tid = threadIdx.x;
  const int lane = tid & 63, w = tid >> 6;
  const int wr = w >> 1, wc = w & 1;
  const int l15 = lane & 15, lhi = lane >> 4;
  const int brow = by * 128;
  const int bcol = bx * 128;
  const int K = NSTATE;
  f32x4 acc[4][4] = {};

  int aoffg[4], boffg[4];
  {
    int r0 = tid >> 3;
    int scb = (tid & 7) ^ (r0 & 7);
    #pragma unroll
    for (int it = 0; it < 4; ++it){
      int row = it*32 + r0;
      aoffg[it] = (brow + row)*K + scb*8;
      boffg[it] = (bcol + row)*K + scb*8;
    }
  }
  int afr[4], bfr[4];
  #pragma unroll
  for (int i = 0; i < 4; ++i){
    int rowA = wr*64 + i*16 + l15;
    afr[i] = rowA*64 + ((lhi ^ (rowA & 7))*8);
    int rowB = wc*64 + i*16 + l15;
    bfr[i] = rowB*64 + ((lhi ^ (rowB & 7))*8);
  }

  for (int kt = 0; kt < K; kt += 64){
    #pragma unroll
    for (int it = 0; it < 4; ++it)
      gld_lds16(A + aoffg[it] + kt, As + it*2048 + tid*8);
    #pragma unroll
    for (int it = 0; it < 4; ++it)
      gld_lds16(Bt + boffg[it] + kt, Bs + it*2048 + tid*8);
    __syncthreads();
    #pragma unroll
    for (int ks = 0; ks < 2; ++ks){
      short8 av[4], bv[4];
      #pragma unroll
      for (int i = 0; i < 4; ++i)
        av[i] = *(const short8*)&As[afr[i] ^ (ks << 5)];
      #pragma unroll
      for (int j = 0; j < 4; ++j)
        bv[j] = *(const short8*)&Bs[bfr[j] ^ (ks << 5)];
      __builtin_amdgcn_s_setprio(1);
      #pragma unroll
      for (int i = 0; i < 4; ++i)
        #pragma unroll
        for (int j = 0; j < 4; ++j)
          acc[i][j] = mfma16x16(av[i], bv[j], acc[i][j]);
      __builtin_amdgcn_s_setprio(0);
    }
    __syncthreads();
  }
  #pragma unroll
  for (int i = 0; i < 4; ++i)
    #pragma unroll
    for (int reg = 0; reg < 4; ++reg){
      int m = brow + wr*64 + i*16 + lhi*4 + reg;
      float* orow = out + (size_t)m*NSTATE + bcol + wc*64;
      #pragma unroll
      for (int j = 0; j < 4; ++j)
        orow[j*16 + l15] = acc[i][j][reg];
    }
}

// ---------------- causal flash attention (32x32 swapped-QK, paired) -------
// R12 structure (paired groups, ones-MFMA denominator, mrun=12 speculative
// exp2) with all loop-invariant addresses hoisted: staging pointers advance
// by +64*ND (K) / +64 (V); one offs[8] table serves both K and V fragment
// reads (identical swizzle formula).
__global__ __launch_bounds__(256)
void flash_attn(const u16* __restrict__ Q, const u16* __restrict__ Kh,
                const u16* __restrict__ Vt, u16* __restrict__ O){
  __shared__ __align__(16) u16 Kbuf[2][64*64];
  __shared__ __align__(16) u16 Vbuf[2][64*64];
  const int gblk = blockIdx.x;
  const int xcd = gblk & 7, gr = gblk >> 3;     // 64 blocks per XCD
  const int bh  = xcd*8 + (gr & 7);             // 8 consecutive bh per XCD
  const int c   = gr >> 3;                      // pair index 0..7
  const int tid = threadIdx.x;
  const int w = tid >> 6, lane = tid & 63;
  const int l31 = lane & 31, hi = lane >> 5;
  const u16* Qb = Q  + (size_t)bh*NS*ND;
  const u16* Kb = Kh + (size_t)bh*NS*ND;
  const u16* Vb = Vt + (size_t)bh*ND*NS;
  const int b = bh >> 4, h = bh & 15;

  short8 ones;
  #pragma unroll
  for (int i = 0; i < 8; ++i) ones[i] = (short)0x3F80;   // bf16 1.0

  // hoisted staging addresses and fragment offsets
  const int r0 = tid >> 3;
  const int scc = (tid & 7) ^ (r0 & 7);
  const u16* ksrc[2]; const u16* vsrc[2];
  #pragma unroll
  for (int i = 0; i < 2; ++i){
    int row = i*32 + r0;
    ksrc[i] = Kb + row*ND + scc*8;
    vsrc[i] = Vb + (size_t)row*NS + scc*8;
  }
  int offs[8];
  #pragma unroll
  for (int a = 0; a < 2; ++a)
    #pragma unroll
    for (int bb = 0; bb < 4; ++bb)
      offs[a*4+bb] = (((a*32 + l31)*128 + bb*32 + hi*16) ^ ((l31 & 7) << 4));

  #pragma unroll 1
  for (int ph = 0; ph < 2; ++ph){
    const int g  = ph ? (15 - c) : c;
    const int qw = g*128 + w*32;
    const int kend_w   = qw + 32;
    const int kend_blk = g*128 + 128;

    short8 qf[4];
    #pragma unroll
    for (int dd = 0; dd < 4; ++dd)
      qf[dd] = *(const short8*)&Qb[(size_t)(qw + l31)*ND + dd*16 + hi*8];

    f32x16 oacc[2] = {};
    f32x16 lacc = {};
    float mrun = 12.0f;

    int cur = 0;
    #pragma unroll
    for (int i = 0; i < 2; ++i){
      gld_lds16(ksrc[i], &Kbuf[0][i*2048 + tid*8]);
      gld_lds16(vsrc[i], &Vbuf[0][i*2048 + tid*8]);
    }
    __syncthreads();

    #pragma unroll 1
    for (int kv0 = 0; kv0 < kend_blk; kv0 += 64){
      if (kv0 + 64 < kend_blk){
        #pragma unroll
        for (int i = 0; i < 2; ++i){
          gld_lds16(ksrc[i] + (kv0 + 64)*ND, &Kbuf[cur^1][i*2048 + tid*8]);
          gld_lds16(vsrc[i] + (kv0 + 64),    &Vbuf[cur^1][i*2048 + tid*8]);
        }
      }
      if (kv0 < kend_w){
        const char* kb = (const char*)&Kbuf[cur][0];
        const char* vb = (const char*)&Vbuf[cur][0];
        short8 kf[8];
        #pragma unroll
        for (int j = 0; j < 8; ++j)
          kf[j] = *(const short8*)(kb + offs[j]);
        f32x16 st0 = {}, st1 = {};
        __builtin_amdgcn_s_setprio(1);
        #pragma unroll
        for (int dd = 0; dd < 4; ++dd) st0 = mfma32(kf[dd],   qf[dd], st0);
        #pragma unroll
        for (int dd = 0; dd < 4; ++dd) st1 = mfma32(kf[4+dd], qf[dd], st1);
        __builtin_amdgcn_s_setprio(0);
        // causal mask (diagonal blocks only)
        if (kv0 + 63 > qw){
          int q = qw + l31;
          #pragma unroll
          for (int r2 = 0; r2 < 16; ++r2){
            int k0 = kv0 + (r2 & 3) + 8*(r2 >> 2) + 4*hi;
            if (k0      > q) st0[r2] = -3.0e30f;
            if (k0 + 32 > q) st1[r2] = -3.0e30f;
          }
        }
        // row max via max3 trees (lane-local + partner shfl)
        float t0 = max3f(st0[0],  st0[1],  st0[2]);
        float t1 = max3f(st0[3],  st0[4],  st0[5]);
        float t2 = max3f(st0[6],  st0[7],  st0[8]);
        float t3 = max3f(st0[9],  st0[10], st0[11]);
        float t4 = max3f(st0[12], st0[13], st0[14]);
        float t5 = max3f(st1[0],  st1[1],  st1[2]);
        float t6 = max3f(st1[3],  st1[4],  st1[5]);
        float t7 = max3f(st1[6],  st1[7],  st1[8]);
        float t8 = max3f(st1[9],  st1[10], st1[11]);
        float t9 = max3f(st1[12], st1[13], st1[14]);
        float u0 = max3f(t0, t1, t2);
        float u1 = max3f(t3, t4, st0[15]);
        float u2 = max3f(t5, t6, t7);
        float u3 = max3f(t8, t9, st1[15]);
        float pm = fmaxf(max3f(u0, u1, u2), u3);
        pm = fmaxf(pm, __shfl_xor(pm, 32));
        // speculative P = exp2(S - mrun)
        #pragma unroll
        for (int r2 = 0; r2 < 16; ++r2){
          st0[r2] = EXP2(st0[r2] - mrun);
          st1[r2] = EXP2(st1[r2] - mrun);
        }
        // rare exact fixup (lane-local)
        if (__any(pm > mrun)){
          float mn = fmaxf(mrun, pm);
          float a  = EXP2(mrun - mn);
          mrun = mn;
          #pragma unroll
          for (int r2 = 0; r2 < 16; ++r2){
            st0[r2] *= a; st1[r2] *= a;
            oacc[0][r2] *= a; oacc[1][r2] *= a;
            lacc[r2] *= a;
          }
        }
        // pack P -> PV B-fragments in-register (cvt_pk + permlane32_swap)
        short8 paf[4];
        #pragma unroll
        for (int sl = 0; sl < 4; ++sl){
          const f32x16& S = (sl < 2) ? st0 : st1;
          const int base = (sl & 1) * 8;
          u32 a0 = cvtpk(S[base+0], S[base+1]);
          u32 b0 = cvtpk(S[base+4], S[base+5]);
          asm("v_permlane32_swap_b32 %0, %1" : "+v"(a0), "+v"(b0));
          u32 a1 = cvtpk(S[base+2], S[base+3]);
          u32 b1 = cvtpk(S[base+6], S[base+7]);
          asm("v_permlane32_swap_b32 %0, %1" : "+v"(a1), "+v"(b1));
          union { u32 u[4]; short8 v; } pk_;
          pk_.u[0] = a0; pk_.u[1] = a1; pk_.u[2] = b0; pk_.u[3] = b1;
          paf[sl] = pk_.v;
        }
        // O^T += V^T . P ; denominator via ones-MFMA
        #pragma unroll
        for (int dh = 0; dh < 2; ++dh){
          short8 vv[4];
          #pragma unroll
          for (int sl = 0; sl < 4; ++sl)
            vv[sl] = *(const short8*)(vb + offs[dh*4+sl]);
          __builtin_amdgcn_s_setprio(1);
          #pragma unroll
          for (int sl = 0; sl < 4; ++sl)
            oacc[dh] = mfma32(vv[sl], paf[sl], oacc[dh]);
          __builtin_amdgcn_s_setprio(0);
        }
        __builtin_amdgcn_s_setprio(1);
        #pragma unroll
        for (int sl = 0; sl < 4; ++sl)
          lacc = mfma32(ones, paf[sl], lacc);
        __builtin_amdgcn_s_setprio(0);
      }
      __syncthreads();
      cur ^= 1;
    }

    // epilogue: O[q][d] = oacc/l ; l = lacc[0] (rows identical by A=ones)
    float inv = 1.0f / lacc[0];
    u16* orow = O + ((size_t)(b*NS + qw + l31))*NSTATE + h*ND;
    #pragma unroll
    for (int dh = 0; dh < 2; ++dh)
      #pragma unroll
      for (int rq = 0; rq < 4; ++rq){
        uint2 pk;
        pk.x = cvtpk(oacc[dh][rq*4+0]*inv, oacc[dh][rq*4+1]*inv);
        pk.y = cvtpk(oacc[dh][rq*4+2]*inv, oacc[dh][rq*4+3]*inv);
        *(uint2*)(orow + dh*32 + rq*8 + hi*4) = pk;
      }
  }
}

// ---------------------------------------------------------------------------
extern "C" void kernel_launch(void* const* d_in, const int* in_sizes, int n_in,
                              void* d_out, int out_size, void* d_ws, size_t ws_size,
                              hipStream_t stream){
  const float* q_src = (const float*)d_in[0];
  const float* k_src = (const float*)d_in[1];
  const float* v_src = (const float*)d_in[2];
  // d_in[3] = position_mask (causal, statically known) — unused
  const float* Wq = (const float*)d_in[4];
  const float* Wk = (const float*)d_in[5];
  const float* Wv = (const float*)d_in[6];
  const float* Wo = (const float*)d_in[7];

  char* ws = (char*)d_ws;
  const size_t MB = 1u << 20;
  if (ws_size < 104*MB) return;   // need 104 MB of scratch

  u16* xq   = (u16*)(ws +  0*MB);   // 16 MB  (bf16 q_src)
  u16* xk   = (u16*)(ws + 16*MB);   // 16 MB  (bf16 k_src)   -> reused as attn out
  u16* xv   = (u16*)(ws + 32*MB);   // 16 MB  (bf16 v_src)
  u16* wq16 = (u16*)(ws + 48*MB);   //  2 MB  } contiguous => Wcat [3072][1024]
  u16* wk16 = (u16*)(ws + 50*MB);   //  2 MB  }
  u16* wv16 = (u16*)(ws + 52*MB);   //  2 MB  }
  u16* wo16 = (u16*)(ws + 54*MB);   //  2 MB
  u16* Qh   = (u16*)(ws + 56*MB);   // 16 MB  [B,H,S,D]
  u16* Kk   = (u16*)(ws + 72*MB);   // 16 MB  [B,H,S,D]
  u16* Vt   = (u16*)(ws + 88*MB);   // 16 MB  [B,H,D,S]  (direct from gemm_qkv)
  u16* Oat  = xk;                   // [B,S,H*D]  (xk dead after QKV gemm)

  cvt_all<<<dim3(28672), dim3(256), 0, stream>>>(q_src, k_src, v_src, Wq, Wk, Wv, Wo,
                                                 xq, xk, xv, wq16, wk16, wv16, wo16);
  gemm_qkv<<<dim3(1536), dim3(256), 0, stream>>>(xq, xk, xv, wq16, Qh, Kk, Vt);
  flash_attn<<<dim3(512), dim3(256), 0, stream>>>(Qh, Kk, Vt, Oat);
  gemm_wo<<<dim3(512), dim3(256), 0, stream>>>(Oat, wo16, (float*)d_out);
}